// Round 11
// baseline (1133.307 us; speedup 1.0000x reference)
//
#include <hip/hip_runtime.h>
#include <math.h>

#define BB 512
#define TT 1024
#define LL 48
#define PF 8            // emission prefetch depth per chain
#define TSTRIDE 49      // padded T row stride: bank = (17*i + j) % 32, conflict-free

__device__ __forceinline__ float readlane_f(float v, int lane) {
    return __int_as_float(__builtin_amdgcn_readlane(__float_as_int(v), lane));
}

// One DPP butterfly/broadcast stage of a full-wave max (register-file cross-lane).
template <int CTRL>
__device__ __forceinline__ float dppmax(float x) {
    int y = __builtin_amdgcn_update_dpp(__float_as_int(x), __float_as_int(x),
                                        CTRL, 0xF, 0xF, false);
    return fmaxf(x, __int_as_float(y));
}

// Wave max of z, then lowest-lane index of bitwise equality (== reference
// first-max argmax; lanes holding -INF never match). ~13 VALU + 1 SALU.
__device__ __forceinline__ int wave_argmax(float z) {
    float r = z;
    r = dppmax<0xB1>(r);    // quad_perm [1,0,3,2] : xor 1
    r = dppmax<0x4E>(r);    // quad_perm [2,3,0,1] : xor 2
    r = dppmax<0x141>(r);   // row_half_mirror     : xor 4
    r = dppmax<0x140>(r);   // row_mirror          : xor 8
    r = dppmax<0x142>(r);   // row_bcast15         : 16->31, 47->63 merge
    r = dppmax<0x143>(r);   // row_bcast31         : lane 63 = full-wave max
    float m = readlane_f(r, 63);
    unsigned long long eq = __ballot(z == m);
    return (int)__builtin_ctzll(eq);     // s_ff1: lowest index wins ties
}

// TWO independent Viterbi chains per wave, statement-interleaved. The R9 step
// body is slim enough (v + ring + pm[12] per chain; tc[48] SHARED) that both
// chains fit in ~150 VGPRs — unlike R1/R2's readlane+scan body (2x s[48])
// which forced the allocator to serialize. The two DS streams interleave in
// the in-order LDS pipe (wA,wB,rA0,rB0,...) so their latencies overlap.
__device__ __attribute__((always_inline)) void step2(
    float& vA, float& vB, const float* __restrict__ tc,
    const float* vbufA, const float* vbufB,
    volatile float* wA, volatile float* wB,  // write handles (lane slot)
    float eA, float eB)
{
    *wA = vA;                              // ds_write_b32 chain A
    *wB = vB;                              // ds_write_b32 chain B
    float pmA[12], pmB[12];
#pragma unroll
    for (int r = 0; r < 12; ++r) {
        float4 qA, qB;
        __builtin_memcpy(&qA, &vbufA[4 * r], 16);   // ds_read_b128, uniform addr
        __builtin_memcpy(&qB, &vbufB[4 * r], 16);
        float a0 = qA.x + tc[4 * r + 0], b0 = qB.x + tc[4 * r + 0];
        float a1 = qA.y + tc[4 * r + 1], b1 = qB.y + tc[4 * r + 1];
        float a2 = qA.z + tc[4 * r + 2], b2 = qB.z + tc[4 * r + 2];
        float a3 = qA.w + tc[4 * r + 3], b3 = qB.w + tc[4 * r + 3];
        pmA[r] = fmaxf(fmaxf(a0, a1), fmaxf(a2, a3));
        pmB[r] = fmaxf(fmaxf(b0, b1), fmaxf(b2, b3));
    }
    float cA0 = fmaxf(fmaxf(pmA[0], pmA[1]), pmA[2]);
    float cB0 = fmaxf(fmaxf(pmB[0], pmB[1]), pmB[2]);
    float cA1 = fmaxf(fmaxf(pmA[3], pmA[4]), pmA[5]);
    float cB1 = fmaxf(fmaxf(pmB[3], pmB[4]), pmB[5]);
    float cA2 = fmaxf(fmaxf(pmA[6], pmA[7]), pmA[8]);
    float cB2 = fmaxf(fmaxf(pmB[6], pmB[7]), pmB[8]);
    float cA3 = fmaxf(fmaxf(pmA[9], pmA[10]), pmA[11]);
    float cB3 = fmaxf(fmaxf(pmB[9], pmB[10]), pmB[11]);
    vA = fmaxf(fmaxf(cA0, cA1), fmaxf(cA2, cA3)) + eA;
    vB = fmaxf(fmaxf(cB0, cB1), fmaxf(cB2, cB3)) + eB;
}

__global__ __launch_bounds__(64)
__attribute__((amdgpu_waves_per_eu(1, 1)))
void viterbi_kernel(
    const float* __restrict__ emissions,   // [B,T,L]
    const float* __restrict__ transitions, // [L,L]
    const float* __restrict__ start_tr,    // [L]
    const float* __restrict__ end_tr,      // [L]
    int* __restrict__ out,                 // [B,T] int32
    float* __restrict__ vws)               // workspace: [B][T][L] viterbi rows
{
    __shared__ float tlds[LL * TSTRIDE];   // T padded for backtrack column reads
    __shared__ __align__(16) float vbufA[64];     // chain-A broadcast buffer
    __shared__ __align__(16) float vbufB[64];     // chain-B broadcast buffer

    const int bA = blockIdx.x * 2;
    const int bB = bA + 1;
    const int j  = threadIdx.x;
    const int jc = (j < LL) ? j : (LL - 1);       // lanes 48-63 mirror lane 47

    // Transition column jc in registers (forward, shared A/B); T into LDS.
    float tc[LL];
#pragma unroll
    for (int i = 0; i < LL; ++i) {
        tc[i] = transitions[i * LL + jc];
        tlds[i * TSTRIDE + jc] = tc[i];    // lanes 48-63 dup-write col 47: same value
    }
#pragma unroll
    for (int i = 0; i < LL; ++i)
        asm volatile("" : "+v"(tc[i]));    // pin: forbid remat-as-load (round-4 mode)

    const float* emA = emissions + (size_t)bA * TT * LL;
    const float* emB = emissions + (size_t)bB * TT * LL;
    float* vgA = vws + (size_t)bA * TT * LL;      // chain A [T][48] rows
    float* vgB = vws + (size_t)bB * TT * LL;

    float vA = start_tr[jc] + emA[jc];
    float vB = start_tr[jc] + emB[jc];
    vgA[jc] = vA;                                  // row 0 (dup lanes: same value)
    vgB[jc] = vB;

    // Emission prefetch rings, one per chain.
    float erA[PF], erB[PF];
#pragma unroll
    for (int k = 0; k < PF; ++k) {
        erA[k] = emA[(size_t)(1 + k) * LL + jc];
        erB[k] = emB[(size_t)(1 + k) * LL + jc];
    }

    volatile float* wA = &vbufA[j];        // per-lane write slots
    volatile float* wB = &vbufB[j];

    // Main loop: blocks of PF with compile-time-constant ring indices.
    int tb = 1;
    for (; tb + PF <= TT; tb += PF) {
#pragma unroll
        for (int k = 0; k < PF; ++k) {
            int t = tb + k;
            float eA = erA[k];
            float eB = erB[k];
            int tn = t + PF; if (tn > TT - 1) tn = TT - 1;   // scalar clamp
            erA[k] = emA[(size_t)tn * LL + jc];    // refills stay in flight
            erB[k] = emB[(size_t)tn * LL + jc];
            step2(vA, vB, tc, vbufA, vbufB, wA, wB, eA, eB);
            vgA[(size_t)t * LL + jc] = vA;         // off-chain coalesced stores
            vgB[(size_t)t * LL + jc] = vB;
        }
    }
    // Tail: steps tb..TT-1 consume ring entries filled by the last refills.
#pragma unroll
    for (int k = 0; k < PF - 1; ++k) {
        int t = tb + k;
        if (t < TT) {
            step2(vA, vB, tc, vbufA, vbufB, wA, wB, erA[k], erB[k]);
            vgA[(size_t)t * LL + jc] = vA;
            vgB[(size_t)t * LL + jc] = vB;
        }
    }

    // ---- final tags: wave-parallel argmax of v + end ----
    float et = end_tr[jc];
    float vfA = (j < LL) ? (vA + et) : -INFINITY;
    float vfB = (j < LL) ? (vB + et) : -INFINITY;
    int tagA = wave_argmax(vfA);                   // uniform (SGPR) tags
    int tagB = wave_argmax(vfB);

    int* obA = out + (size_t)bA * TT;
    int* obB = out + (size_t)bB * TT;
    if (j == 0) {
        obA[TT - 1] = tagA;
        obB[TT - 1] = tagB;
    }

    // ---- backtrack: both chains interleaved (independent tag chains) ----
    // tag_p = argmax_i( v_p[i] + T[i][tag_{p+1}] ), p = T-2 .. 0.
    for (int hi = TT - 2; hi >= 0; hi -= 32) {
        int lo = hi - 31; if (lo < 0) lo = 0;
        int n = hi - lo + 1;                       // wave-uniform

        float vrA[32], vrB[32];
#pragma unroll
        for (int k = 31; k >= 0; --k) {            // issue order == consume order
            if (k < n) {
                vrA[k] = vgA[(size_t)(lo + k) * LL + jc];
                vrB[k] = vgB[(size_t)(lo + k) * LL + jc];
            }
        }

        int outA = 0, outB = 0;
#pragma unroll
        for (int k = 31; k >= 0; --k) {
            if (k < n) {
                // lane i reads T[i][tag]: dwords (17*i + tag) % 32 -> no conflicts
                float tcA = tlds[jc * TSTRIDE + tagA];
                float tcB = tlds[jc * TSTRIDE + tagB];
                float zA = (j < LL) ? (vrA[k] + tcA) : -INFINITY;
                float zB = (j < LL) ? (vrB[k] + tcB) : -INFINITY;
                tagA = wave_argmax(zA);            // two independent chains:
                tagB = wave_argmax(zB);            // latencies overlap
                outA = (j == k) ? tagA : outA;     // tag is SGPR -> one cndmask
                outB = (j == k) ? tagB : outB;
            }
        }
        if (j < n) {
            obA[lo + j] = outA;
            obB[lo + j] = outB;
        }
    }
}

extern "C" void kernel_launch(void* const* d_in, const int* in_sizes, int n_in,
                              void* d_out, int out_size, void* d_ws, size_t ws_size,
                              hipStream_t stream) {
    const float* emissions   = (const float*)d_in[0];
    // d_in[1] = mask — unused by the reference decode body
    const float* transitions = (const float*)d_in[2];
    const float* start_tr    = (const float*)d_in[3];
    const float* end_tr      = (const float*)d_in[4];
    int* out = (int*)d_out;

    // Viterbi rows: B * T * L * 4 = 100,663,296 B in the provided workspace.
    float* vws = (float*)d_ws;

    viterbi_kernel<<<dim3(BB / 2), dim3(64), 0, stream>>>(
        emissions, transitions, start_tr, end_tr, out, vws);
}

// Round 13
// 578.481 us; speedup vs baseline: 1.9591x; 1.9591x over previous
//
#include <hip/hip_runtime.h>
#include <math.h>

#define BB 512
#define TT 1024
#define LL 48
#define PF 8            // emission prefetch depth (loads in flight)
#define TSTRIDE 49      // padded T row stride: bank = (17*i + j) % 32, conflict-free

__device__ __forceinline__ float readlane_f(float v, int lane) {
    return __int_as_float(__builtin_amdgcn_readlane(__float_as_int(v), lane));
}

template <int CTRL>
__device__ __forceinline__ unsigned dppu(unsigned x) {
    return (unsigned)__builtin_amdgcn_update_dpp((int)x, (int)x, CTRL, 0xF, 0xF, false);
}

// One DPP butterfly/broadcast stage of a full-wave max (register-file cross-lane).
template <int CTRL>
__device__ __forceinline__ float dppmax(float x) {
    int y = __builtin_amdgcn_update_dpp(__float_as_int(x), __float_as_int(x),
                                        CTRL, 0xF, 0xF, false);
    return fmaxf(x, __int_as_float(y));
}

// Partner-exchange via v_permlane16/32_swap with FORCED-DISTINCT operands.
// R12 failure: `b = a` (plain IR copy) let regalloc coalesce both swap
// operands into ONE physical VGPR -> swap-with-itself scrambled the data AND
// the calibration. The early-clobber opaque v_mov makes b an asm-defined
// value the allocator cannot coalesce with a.
__device__ __forceinline__ void pl16_swap2(unsigned& a, unsigned& b, unsigned x) {
    a = x;
    asm("v_mov_b32 %0, %1" : "=&v"(b) : "v"(a));
    asm("v_permlane16_swap_b32 %0, %1" : "+v"(a), "+v"(b));
}
__device__ __forceinline__ void pl32_swap2(unsigned& a, unsigned& b, unsigned x) {
    a = x;
    asm("v_mov_b32 %0, %1" : "=&v"(b) : "v"(a));
    asm("v_permlane32_swap_b32 %0, %1" : "+v"(a), "+v"(b));
}

// Wave max of z, then lowest-lane index of bitwise equality (== reference
// first-max argmax; lanes holding -INF never match). ~13 VALU + 1 SALU.
__device__ __forceinline__ int wave_argmax(float z) {
    float r = z;
    r = dppmax<0xB1>(r);    // quad_perm [1,0,3,2]
    r = dppmax<0x4E>(r);    // quad_perm [2,3,0,1]
    r = dppmax<0x141>(r);   // row_half_mirror
    r = dppmax<0x140>(r);   // row_mirror
    r = dppmax<0x142>(r);   // row_bcast15
    r = dppmax<0x143>(r);   // row_bcast31 : lane 63 = full-wave max
    float m = readlane_f(r, 63);
    unsigned long long eq = __ballot(z == m);
    return (int)__builtin_ctzll(eq);     // s_ff1: lowest index wins ties
}

// Row-gather butterfly: after this, g[p] at lane j holds x of lane src(p,j),
// where {src(p,j) : p=0..15} = the 16 lanes of j's row. src(p,j) is never
// hardcoded — callers self-calibrate by running bfly16 on the lane index.
__device__ __forceinline__ void bfly16(unsigned x, unsigned g[16]) {
    g[0] = x;
    g[1] = dppu<0xB1>(g[0]);
    g[2] = dppu<0x4E>(g[0]);
    g[3] = dppu<0x4E>(g[1]);
#pragma unroll
    for (int p = 0; p < 4; ++p) g[4 + p] = dppu<0x141>(g[p]);
#pragma unroll
    for (int p = 0; p < 8; ++p) g[8 + p] = dppu<0x140>(g[p]);
}

__device__ __forceinline__ float max16(const float s[16]) {
    float m0 = fmaxf(fmaxf(s[0], s[1]), s[2]);
    float m1 = fmaxf(fmaxf(s[3], s[4]), s[5]);
    float m2 = fmaxf(fmaxf(s[6], s[7]), s[8]);
    float m3 = fmaxf(fmaxf(s[9], s[10]), s[11]);
    float m4 = fmaxf(fmaxf(s[12], s[13]), s[14]);
    return fmaxf(fmaxf(fmaxf(m0, m1), fmaxf(m2, m3)), fmaxf(m4, s[15]));
}

// Forward stores VALUES ONLY; backtrack recomputes the one on-path argmax per
// step (bitwise-identical floats, ffs tie-break).
//
// Step = pure VALU: 15-DPP row-gather of v + four pre-permuted transition
// tables tcp_d[p] = T[src(p,j)][dst_d(j)], dst = {j, j^16, j^32, j^48} ->
// 4 per-row partial maxes -> combined across rows with 2 permlane16_swap +
// 1 permlane32_swap. No LDS (R9: 670 cyc/step), no readlane (R0: 800).
// Every real sum is v[i]+T[i][j] in f32; duplicate i=47 entries from the
// lane-48..63 mirrors are harmless under max -> bitwise == reference.
__global__ __launch_bounds__(64)
__attribute__((amdgpu_waves_per_eu(1, 1)))
void viterbi_kernel(
    const float* __restrict__ emissions,   // [B,T,L]
    const float* __restrict__ transitions, // [L,L]
    const float* __restrict__ start_tr,    // [L]
    const float* __restrict__ end_tr,      // [L]
    int* __restrict__ out,                 // [B,T] int32
    float* __restrict__ vws)               // workspace: [B][T][L] viterbi rows
{
    __shared__ float tlds[LL * TSTRIDE];   // T padded for backtrack column reads

    const int b  = blockIdx.x;
    const int j  = threadIdx.x;
    const int jc = (j < LL) ? j : (LL - 1);       // lanes 48-63 mirror lane 47

    // T into LDS (backtrack only).
#pragma unroll
    for (int i = 0; i < LL; ++i)
        tlds[i * TSTRIDE + jc] = transitions[i * LL + jc];

    // ---- self-calibration (runs on lane indices, with the FIXED primitive) ----
    unsigned gi[16];
    bfly16((unsigned)j, gi);                      // gi[p] = src(p, j), exact
#pragma unroll
    for (int p = 0; p < 16; ++p) asm("" : "+v"(gi[p]));

    unsigned ca, cb;
    pl16_swap2(ca, cb, (unsigned)j);
    const bool useA16 = (ca == (unsigned)(j ^ 16));   // per-lane: which output
    unsigned da, db;                                   //   holds the partner
    pl32_swap2(da, db, (unsigned)j);
    const bool useA32 = (da == (unsigned)(j ^ 32));

    // ---- pre-permuted transition tables: tcp_d[p] = T[src(p,j)][dst_d] ----
    const int d0 = jc;
    const int d1 = min(j ^ 16, LL - 1);
    const int d2 = min(j ^ 32, LL - 1);
    const int d3 = min(j ^ 48, LL - 1);
    float tcp0[16], tcp1[16], tcp2[16], tcp3[16];
#pragma unroll
    for (int p = 0; p < 16; ++p) {
        const int src = min((int)gi[p], LL - 1);
        const float* trow = transitions + src * LL;
        tcp0[p] = trow[d0];
        tcp1[p] = trow[d1];
        tcp2[p] = trow[d2];
        tcp3[p] = trow[d3];
    }
#pragma unroll
    for (int p = 0; p < 16; ++p) {         // pin: forbid remat-as-load (R4 mode)
        asm("" : "+v"(tcp0[p]));
        asm("" : "+v"(tcp1[p]));
        asm("" : "+v"(tcp2[p]));
        asm("" : "+v"(tcp3[p]));
    }

    const float* em = emissions + (size_t)b * TT * LL;
    float* vr_g = vws + (size_t)b * TT * LL;      // this chain's [T][48] rows

    float v = start_tr[jc] + em[jc];
    vr_g[jc] = v;                                  // row 0 (dup lanes: same value)

    // PF-deep emission prefetch ring.
    float er[PF];
#pragma unroll
    for (int k = 0; k < PF; ++k)
        er[k] = em[(size_t)(1 + k) * LL + jc];

    // One value-only Viterbi step: pure VALU on the chain.
    auto step = [&](int t, float e) {
        unsigned g[16];
        bfly16(__float_as_uint(v), g);             // row-gather of v

        float s[16];
#pragma unroll
        for (int p = 0; p < 16; ++p) s[p] = __uint_as_float(g[p]) + tcp0[p];
        const float P0 = max16(s);                 // own-row srcs, dest j
#pragma unroll
        for (int p = 0; p < 16; ++p) s[p] = __uint_as_float(g[p]) + tcp1[p];
        const float P1 = max16(s);                 // own-row srcs, dest j^16
#pragma unroll
        for (int p = 0; p < 16; ++p) s[p] = __uint_as_float(g[p]) + tcp2[p];
        const float P2 = max16(s);                 // own-row srcs, dest j^32
#pragma unroll
        for (int p = 0; p < 16; ++p) s[p] = __uint_as_float(g[p]) + tcp3[p];
        const float P3 = max16(s);                 // own-row srcs, dest j^48

        // cross ^16: deliver P1/P3 to the ^16 partner lane
        unsigned a1, b1; pl16_swap2(a1, b1, __float_as_uint(P1));
        const float r1 = useA16 ? __uint_as_float(a1) : __uint_as_float(b1);
        unsigned a3, b3; pl16_swap2(a3, b3, __float_as_uint(P3));
        const float r3 = useA16 ? __uint_as_float(a3) : __uint_as_float(b3);
        const float Q0 = fmaxf(P0, r1);            // rows {r, r^1}, dest j
        const float Q2 = fmaxf(P2, r3);            // rows {r, r^1}, dest j^32

        // cross ^32: receive the other half's partial for dest j
        unsigned a2, b2; pl32_swap2(a2, b2, __float_as_uint(Q2));
        const float r2 = useA32 ? __uint_as_float(a2) : __uint_as_float(b2);

        v = fmaxf(Q0, r2) + e;                     // chain continues here
        vr_g[(size_t)t * LL + jc] = v;             // off-chain coalesced store
    };

    // Main loop: blocks of PF with compile-time-constant ring indices.
    int tb = 1;
    for (; tb + PF <= TT; tb += PF) {
#pragma unroll
        for (int k = 0; k < PF; ++k) {
            int t = tb + k;
            float e = er[k];
            int tn = t + PF; if (tn > TT - 1) tn = TT - 1;   // scalar clamp
            er[k] = em[(size_t)tn * LL + jc];      // refill: PF loads in flight
            step(t, e);
        }
    }
#pragma unroll
    for (int k = 0; k < PF - 1; ++k) {
        int t = tb + k;
        if (t < TT) step(t, er[k]);
    }

    // ---- final tag: wave-parallel argmax of v + end ----
    float vf = (j < LL) ? (v + end_tr[jc]) : -INFINITY;
    int tag = wave_argmax(vf);                     // uniform (SGPR) tag

    int* ob = out + (size_t)b * TT;
    if (j == 0) ob[TT - 1] = tag;

    // ---- backtrack: recompute argmax only along the path ----
    // tag_p = argmax_i( v_p[i] + T[i][tag_{p+1}] ), p = T-2 .. 0.
    for (int hi = TT - 2; hi >= 0; hi -= 32) {
        int lo = hi - 31; if (lo < 0) lo = 0;
        int n = hi - lo + 1;                       // wave-uniform

        float vr[32];
#pragma unroll
        for (int k = 31; k >= 0; --k)              // issue order == consume order
            if (k < n) vr[k] = vr_g[(size_t)(lo + k) * LL + jc];

        int outv = 0;
#pragma unroll
        for (int k = 31; k >= 0; --k) {
            if (k < n) {
                // lane i reads T[i][tag]: dwords (17*i + tag) % 32 -> no conflicts
                float tcol = tlds[jc * TSTRIDE + tag];
                float z = (j < LL) ? (vr[k] + tcol) : -INFINITY;
                tag = wave_argmax(z);              // chain: ds_read+add+dpp+ballot
                outv = (j == k) ? tag : outv;      // tag is SGPR -> one cndmask
            }
        }
        if (j < n) ob[lo + j] = outv;
    }
}

extern "C" void kernel_launch(void* const* d_in, const int* in_sizes, int n_in,
                              void* d_out, int out_size, void* d_ws, size_t ws_size,
                              hipStream_t stream) {
    const float* emissions   = (const float*)d_in[0];
    // d_in[1] = mask — unused by the reference decode body
    const float* transitions = (const float*)d_in[2];
    const float* start_tr    = (const float*)d_in[3];
    const float* end_tr      = (const float*)d_in[4];
    int* out = (int*)d_out;

    // Viterbi rows: B * T * L * 4 = 100,663,296 B in the provided workspace.
    float* vws = (float*)d_ws;

    viterbi_kernel<<<dim3(BB), dim3(64), 0, stream>>>(
        emissions, transitions, start_tr, end_tr, out, vws);
}